// Round 5
// baseline (208.564 us; speedup 1.0000x reference)
//
#include <hip/hip_runtime.h>
#include <math.h>

#define B_    4
#define CIN_  128
#define COUT_ 128
#define H_    128
#define W_    128
#define HW_   (H_*W_)
#define KK_   9

typedef __attribute__((ext_vector_type(8))) short short8;
typedef __attribute__((ext_vector_type(4))) float f32x4;
typedef _Float16 h8 __attribute__((ext_vector_type(8)));
typedef float f2v __attribute__((ext_vector_type(2), aligned(4)));  // 4B-aligned pair load

static __device__ __forceinline__ unsigned f2bf(float f) {
    union { float f; unsigned u; } v; v.f = f;
    return (v.u + 0x7fffu + ((v.u >> 16) & 1u)) >> 16;
}
static __device__ __forceinline__ unsigned short f2h(float f) {
    union { _Float16 h; unsigned short u; } v; v.h = (_Float16)f;
    return v.u;
}

// K-chunk order (both GEMMs): q = cblock*9 + tap (channel-outer, tap inner).

// ---------------------------------------------------------------------------
// Prep (fused): bx<512 -> transpose inp NCHW f32 -> NHWC f16;
//               bx<584 -> w_dc swizzle (f16); else -> w_off swizzle (bf16).
// One launch replaces three (launch-boundary cost dominated the pipeline).
// ---------------------------------------------------------------------------
__global__ __launch_bounds__(256) void prep_kernel(
    const float* __restrict__ inp, const float* __restrict__ w_dc,
    const float* __restrict__ w_off, unsigned short* __restrict__ inpT,
    unsigned short* __restrict__ w_swz, unsigned short* __restrict__ woff_swz)
{
    const int bx = blockIdx.x;
    const int tid = threadIdx.x;
    __shared__ unsigned short s_T[128 * 142];   // 36352 B (tpose branch only)

    if (bx < 512) {
        // ---- transpose: block = (b, y); LDS tile [128x][142c] ----
        const int b = bx >> 7, y = bx & 127;
        const float* src = inp + (size_t)b * CIN_ * HW_ + y * W_;
        const int xs = (tid & 63) * 2;
        const int c0 = tid >> 6;
#pragma unroll 4
        for (int p = 0; p < 32; ++p) {
            int c = c0 + 4 * p;
            f2v d = *(const f2v*)(src + (size_t)c * HW_ + xs);
            s_T[xs * 142 + c]       = f2h(d.x);
            s_T[(xs + 1) * 142 + c] = f2h(d.y);
        }
        __syncthreads();
        unsigned short* dst = inpT + (size_t)bx * (W_ * CIN_);   // [x][c]
        const int cs = (tid & 15) * 8;
        const int x0 = tid >> 4;
#pragma unroll
        for (int p = 0; p < 8; ++p) {
            int x = x0 + 16 * p;
            unsigned r[4];
#pragma unroll
            for (int j = 0; j < 4; ++j) {
                unsigned lo = s_T[x * 142 + cs + 2 * j];
                unsigned hi = s_T[x * 142 + cs + 2 * j + 1];
                r[j] = lo | (hi << 16);
            }
            *(int4*)(dst + (size_t)x * CIN_ + cs) = make_int4(r[0], r[1], r[2], r[3]);
        }
    } else if (bx < 584) {
        // ---- w_dc swizzle -> f16 A-fragments ----
        int idx = (bx - 512) * 256 + tid;   // [0, 36*8*64)
        int q   = idx >> 9;
        int rem = idx & 511;
        int ocb = rem >> 6;
        int l   = rem & 63;
        int cbq = q / 9;
        int k   = q - cbq * 9;
        int cb  = (cbq << 5) + ((l >> 4) << 3);
        int oc  = (ocb << 4) + (l & 15);
        unsigned r[4];
#pragma unroll
        for (int j = 0; j < 4; ++j) {
            float f0 = w_dc[((size_t)(oc * CIN_ + cb + 2 * j    )) * KK_ + k];
            float f1 = w_dc[((size_t)(oc * CIN_ + cb + 2 * j + 1)) * KK_ + k];
            r[j] = (unsigned)f2h(f0) | ((unsigned)f2h(f1) << 16);
        }
        *(int4*)&w_swz[(size_t)idx * 8] = make_int4(r[0], r[1], r[2], r[3]);
    } else {
        // ---- w_off swizzle -> bf16 A-fragments, oc padded 27->32 ----
        int idx = (bx - 584) * 256 + tid;   // [0, 36*2*64)
        int q   = idx >> 7;
        int rem = idx & 127;
        int l   = rem & 63;
        int cbq = q / 9;
        int k   = q - cbq * 9;
        int cb  = (cbq << 5) + ((l >> 4) << 3);
        int oc  = ((rem >> 6) << 4) + (l & 15);
        unsigned r[4];
#pragma unroll
        for (int j = 0; j < 4; ++j) {
            float f0 = 0.f, f1 = 0.f;
            if (oc < 27) {
                f0 = w_off[((size_t)(oc * CIN_ + cb + 2 * j    )) * KK_ + k];
                f1 = w_off[((size_t)(oc * CIN_ + cb + 2 * j + 1)) * KK_ + k];
            }
            r[j] = f2bf(f0) | (f2bf(f1) << 16);
        }
        *(int4*)&woff_swz[(size_t)idx * 8] = make_int4(r[0], r[1], r[2], r[3]);
    }
}

// ---------------------------------------------------------------------------
// Fused main: offset-conv GEMM (phase 1, bf16 MFMA, result kept in LDS) ->
// bilinear metadata (from LDS) -> deformable-conv GEMM (phase 2, f16 MFMA,
// channel-last gathers). dcn block (b,h,pw0) consumes exactly offset block
// (b,h,w0)'s output, so fusion removes the offm global round-trip AND the
// grid-wide sync between the two GEMMs (blocks now flow independently).
// Phase-2 LDS-write lane mapping px=tid&63, cs=tid>>6: quarter-wave dword
// starts 20*px%32 evenly spaced -> 2 lanes/bank = conflict-free (was 3-5).
// LDS: region0 s_F[3][66][40] (15872B, reused as s_V[2][64][40]) |
//      offv[27][65] f32 (7040B) | s_midx (4608B) | s_mwgt (9216B) = 36736B.
// ---------------------------------------------------------------------------
__global__ __launch_bounds__(256, 4) void fused_kernel(
    const float* __restrict__ feat, const unsigned short* __restrict__ inpT,
    const unsigned short* __restrict__ woff_swz, const unsigned short* __restrict__ w_swz,
    const float* __restrict__ b_off, const float* __restrict__ b_dc,
    float* __restrict__ out)
{
    const int tid = threadIdx.x;
    const int bx = blockIdx.x;
    const int lidx = ((bx & 7) << 7) | (bx >> 3);   // XCD swizzle, 1024 blocks
    const int b  = lidx >> 8;
    const int h  = (lidx & 255) >> 1;
    const int w0 = (lidx & 1) << 6;                 // == pw0

    __shared__ __align__(16) char smem[36736];
    unsigned short (*s_F)[66][40] = (unsigned short (*)[66][40])smem;   // phase 1
    unsigned short *s_Vb          = (unsigned short*)smem;              // phase 2 [2][64][40]
    float  (*offv)[65]            = (float (*)[65])(smem + 15872);
    int2   *s_midx                = (int2  *)(smem + 15872 + 7040);
    float4 *s_mwgt                = (float4*)(smem + 15872 + 7040 + 4608);

    const int lane = tid & 63;
    const int wave = tid >> 6;
    const int kg = lane >> 4, pn = lane & 15;

    // ================= phase 1: offset conv (bf16 MFMA) =================
    {
        const float* fbase = feat + (size_t)b * CIN_ * HW_;
        f32x4 acc[2];
        acc[0] = (f32x4){0.f, 0.f, 0.f, 0.f};
        acc[1] = (f32x4){0.f, 0.f, 0.f, 0.f};

        for (int cb = 0; cb < 4; ++cb) {
            if (cb) __syncthreads();       // taps of cb-1 done reading s_F

#pragma unroll
            for (int r = 0; r < 3; ++r) {
                const int y = h + r - 1;
                const bool yv = (unsigned)y < (unsigned)H_;   // block-uniform
                const float* rowp = fbase + (size_t)(cb << 5) * HW_ + y * W_;
#pragma unroll
                for (int j = 0; j < 4; ++j) {
                    int item = tid + (j << 8);
                    int c = item >> 5;
                    int e = item & 31;
                    int x0 = w0 - 1 + 2 * e;
                    int hx = min(max(x0, 0), W_ - 2);
                    float v0 = 0.f, v1 = 0.f;
                    if (yv) {
                        f2v p = *(const f2v*)(rowp + (size_t)c * HW_ + hx);
                        v0 = (x0 == hx) ? p.x : ((x0 < hx) ? 0.f : p.y);
                        v1 = (x0 == hx) ? p.y : ((x0 < hx) ? p.x : 0.f);
                    }
                    s_F[r][2 * e    ][c] = (unsigned short)f2bf(v0);
                    s_F[r][2 * e + 1][c] = (unsigned short)f2bf(v1);
                }
                if (tid < 32) {
                    int c = tid;
                    int x0 = w0 + 63;
                    int hx = min(x0, W_ - 2);
                    float v0 = 0.f, v1 = 0.f;
                    if (yv) {
                        f2v p = *(const f2v*)(rowp + (size_t)c * HW_ + hx);
                        v0 = (x0 == hx) ? p.x : p.y;
                        v1 = (x0 == hx) ? p.y : 0.f;
                    }
                    s_F[r][64][c] = (unsigned short)f2bf(v0);
                    s_F[r][65][c] = (unsigned short)f2bf(v1);
                }
            }
            __syncthreads();

            const int qb2 = cb * 18;
            const short8* wb = (const short8*)woff_swz;
            short8 a0 = wb[(size_t)(qb2    ) * 64 + lane];
            short8 a1 = wb[(size_t)(qb2 + 1) * 64 + lane];
#pragma unroll
            for (int k = 0; k < 9; ++k) {
                const int ky = k / 3, kx = k - 3 * ky;
                short8 bfr = *(const short8*)&s_F[ky][wave * 16 + pn + kx][kg * 8];
                short8 na0, na1;
                if (k < 8) {
                    na0 = wb[(size_t)(qb2 + 2 * k + 2) * 64 + lane];
                    na1 = wb[(size_t)(qb2 + 2 * k + 3) * 64 + lane];
                }
                acc[0] = __builtin_amdgcn_mfma_f32_16x16x32_bf16(a0, bfr, acc[0], 0, 0, 0);
                acc[1] = __builtin_amdgcn_mfma_f32_16x16x32_bf16(a1, bfr, acc[1], 0, 0, 0);
                if (k < 8) { a0 = na0; a1 = na1; }
            }
        }

        // epilogue -> offv (LDS, f32 — identical numerics to old global offm)
        const int row0 = (lane >> 4) << 2;
        const int col  = lane & 15;
        const int pwl  = wave * 16 + col;
#pragma unroll
        for (int mt = 0; mt < 2; ++mt) {
#pragma unroll
            for (int i = 0; i < 4; ++i) {
                int oc = mt * 16 + row0 + i;
                if (oc < 27) {
                    float v = acc[mt][i] + b_off[oc];
                    if (oc >= 18) v = 1.f / (1.f + __expf(-v));
                    offv[oc][pwl] = v;
                }
            }
        }
    }
    __syncthreads();   // offv visible to all

    // ================= bilinear metadata: 9 taps x 64 px =================
    for (int i = tid; i < 576; i += 256) {
        int k = i >> 6, p = i & 63;
        int ky = k / 3, kx = k - ky * 3;
        int pw = w0 + p;
        float offy = offv[2 * k    ][p];
        float offx = offv[2 * k + 1][p];
        float mask = offv[18 + k   ][p];
        float py  = offy + (float)(h  + ky - 1);
        float px_ = offx + (float)(pw + kx - 1);
        float y0f = floorf(py), x0f = floorf(px_);
        float ly = py - y0f, lx = px_ - x0f;
        int y0 = (int)y0f, x0 = (int)x0f;
        int y1 = y0 + 1;
        int hx = min(max(x0, 0), W_ - 2);
        float wlo = 0.f, whi = 0.f;
        if (x0 == hx)          { wlo = 1.f - lx; whi = lx; }     // normal
        else if (x0 == hx - 1) { wlo = lx; }                     // x0 == -1
        else if (x0 == hx + 1) { whi = 1.f - lx; }               // x0 == W-1
        float wt_top = ((unsigned)y0 < (unsigned)H_) ? (1.f - ly) * mask : 0.f;
        float wt_bot = ((unsigned)y1 < (unsigned)H_) ? ly * mask : 0.f;
        int cy0 = min(max(y0, 0), H_ - 1), cy1 = min(max(y1, 0), H_ - 1);
        s_midx[i] = make_int2(cy0 * W_ + hx, cy1 * W_ + hx);
        s_mwgt[i] = make_float4(wt_top * wlo, wt_top * whi,
                                wt_bot * wlo, wt_bot * whi);
    }
    __syncthreads();   // meta visible; offv dead; region0 reusable as s_V

    // ================= phase 2: deformable conv (f16 MFMA) =================
    const int px = tid & 63;              // gather pixel (bank-conflict-free map)
    const int cs = tid >> 6;              // channel quarter (8 ch) == wave
    const char* inpTb = (const char*)(inpT + (size_t)b * CIN_ * HW_);

    f32x4 acc2[2][4];
#pragma unroll
    for (int mt = 0; mt < 2; ++mt)
#pragma unroll
        for (int nt = 0; nt < 4; ++nt) acc2[mt][nt] = (f32x4){0.f, 0.f, 0.f, 0.f};

    h8 pf0, pf1, pf2, pf3;   // corners: (y0,x0),(y0,x1),(y1,x0),(y1,x1)

    auto issue = [&](int qq) {
        int cbq = qq / 9;
        int k   = qq - cbq * 9;
        int2 id = s_midx[(k << 6) + px];
        int coff = (cbq << 6) + (cs << 4);
        const char* g0 = inpTb + ((size_t)(unsigned)id.x << 8) + coff;
        const char* g1 = inpTb + ((size_t)(unsigned)id.y << 8) + coff;
        pf0 = *(const h8*)(g0);
        pf1 = *(const h8*)(g0 + 256);     // x+1: +CIN_*2B
        pf2 = *(const h8*)(g1);
        pf3 = *(const h8*)(g1 + 256);
    };

    issue(0);

    for (int q = 0; q < 36; ++q) {
        int k = q - (q / 9) * 9;

        // consume prefetched corners: packed-f16 bilinear
        float4 wt = s_mwgt[(k << 6) + px];
        h8 v = pf0 * (_Float16)wt.x;
        v += pf1 * (_Float16)wt.y;
        v += pf2 * (_Float16)wt.z;
        v += pf3 * (_Float16)wt.w;

        // A-fragments FIRST (so MFMA's vmcnt wait keeps gathers in flight)
        const h8* wp = (const h8*)w_swz + (size_t)(q * 8 + wave * 2) * 64 + lane;
        h8 af0 = wp[0];
        h8 af1 = wp[64];

        *(h8*)&s_Vb[(size_t)(q & 1) * (64 * 40) + px * 40 + (cs << 3)] = v;

        int qn = (q + 1 < 36) ? q + 1 : 35;
        issue(qn);                         // gathers for next chunk in flight

        __syncthreads();                   // buf[q&1] complete; prev reads done

#pragma unroll
        for (int nt = 0; nt < 4; ++nt) {
            h8 bfr = *(const h8*)&s_Vb[(size_t)(q & 1) * (64 * 40) + (nt * 16 + pn) * 40 + kg * 8];
            acc2[0][nt] = __builtin_amdgcn_mfma_f32_16x16x32_f16(af0, bfr, acc2[0][nt], 0, 0, 0);
            acc2[1][nt] = __builtin_amdgcn_mfma_f32_16x16x32_f16(af1, bfr, acc2[1][nt], 0, 0, 0);
        }
    }

    const int row0 = (lane >> 4) << 2;
    const int col  = lane & 15;
#pragma unroll
    for (int mt = 0; mt < 2; ++mt) {
#pragma unroll
        for (int nt = 0; nt < 4; ++nt) {
            int pw = w0 + nt * 16 + col;
#pragma unroll
            for (int i = 0; i < 4; ++i) {
                int oc = wave * 32 + mt * 16 + row0 + i;
                out[((size_t)(b * COUT_ + oc)) * HW_ + h * W_ + pw] =
                    acc2[mt][nt][i] + b_dc[oc];
            }
        }
    }
}

extern "C" void kernel_launch(void* const* d_in, const int* in_sizes, int n_in,
                              void* d_out, int out_size, void* d_ws, size_t ws_size,
                              hipStream_t stream)
{
    const float* inp   = (const float*)d_in[0];
    const float* feat  = (const float*)d_in[1];
    const float* w_off = (const float*)d_in[2];
    const float* b_off = (const float*)d_in[3];
    const float* w_dc  = (const float*)d_in[4];
    const float* b_dc  = (const float*)d_in[5];
    float* out  = (float*)d_out;
    unsigned short* w_swz    = (unsigned short*)d_ws;                        // 288 KB (f16)
    unsigned short* woff_swz = (unsigned short*)((char*)d_ws + 294912);      // 72 KB (bf16)
    unsigned short* inpT     = (unsigned short*)((char*)d_ws + 368640);      // 16 MB (f16 NHWC)

    prep_kernel<<<dim3(602), dim3(256), 0, stream>>>(inp, w_dc, w_off, inpT, w_swz, woff_swz);
    fused_kernel<<<dim3(1024), dim3(256), 0, stream>>>(feat, inpT, woff_swz, w_swz, b_off, b_dc, out);
}

// Round 6
// 171.335 us; speedup vs baseline: 1.2173x; 1.2173x over previous
//
#include <hip/hip_runtime.h>
#include <math.h>

#define B_    4
#define CIN_  128
#define COUT_ 128
#define H_    128
#define W_    128
#define HW_   (H_*W_)
#define KK_   9

typedef __attribute__((ext_vector_type(8))) short short8;
typedef __attribute__((ext_vector_type(4))) float f32x4;
typedef _Float16 h8 __attribute__((ext_vector_type(8)));
typedef float f2v __attribute__((ext_vector_type(2), aligned(4)));  // 4B-aligned pair load

static __device__ __forceinline__ unsigned f2bf(float f) {
    union { float f; unsigned u; } v; v.f = f;
    return (v.u + 0x7fffu + ((v.u >> 16) & 1u)) >> 16;
}
static __device__ __forceinline__ unsigned short f2h(float f) {
    union { _Float16 h; unsigned short u; } v; v.h = (_Float16)f;
    return v.u;
}

// K-chunk order (both GEMMs): q = cblock*9 + tap (channel-outer, tap inner).

// ---------------------------------------------------------------------------
// Prep (fused): bx<512 -> transpose inp NCHW f32 -> NHWC f16;
//               bx<584 -> w_dc swizzle (f16); else -> w_off swizzle (bf16).
// ---------------------------------------------------------------------------
__global__ __launch_bounds__(256) void prep_kernel(
    const float* __restrict__ inp, const float* __restrict__ w_dc,
    const float* __restrict__ w_off, unsigned short* __restrict__ inpT,
    unsigned short* __restrict__ w_swz, unsigned short* __restrict__ woff_swz)
{
    const int bx = blockIdx.x;
    const int tid = threadIdx.x;
    __shared__ unsigned short s_T[128 * 142];   // 36352 B (tpose branch only)

    if (bx < 512) {
        // ---- transpose: block = (b, y); LDS tile [128x][142c] ----
        const int b = bx >> 7, y = bx & 127;
        const float* src = inp + (size_t)b * CIN_ * HW_ + y * W_;
        const int xs = (tid & 63) * 2;
        const int c0 = tid >> 6;
#pragma unroll 4
        for (int p = 0; p < 32; ++p) {
            int c = c0 + 4 * p;
            f2v d = *(const f2v*)(src + (size_t)c * HW_ + xs);
            s_T[xs * 142 + c]       = f2h(d.x);
            s_T[(xs + 1) * 142 + c] = f2h(d.y);
        }
        __syncthreads();
        unsigned short* dst = inpT + (size_t)bx * (W_ * CIN_);   // [x][c]
        const int cs = (tid & 15) * 8;
        const int x0 = tid >> 4;
#pragma unroll
        for (int p = 0; p < 8; ++p) {
            int x = x0 + 16 * p;
            unsigned r[4];
#pragma unroll
            for (int j = 0; j < 4; ++j) {
                unsigned lo = s_T[x * 142 + cs + 2 * j];
                unsigned hi = s_T[x * 142 + cs + 2 * j + 1];
                r[j] = lo | (hi << 16);
            }
            *(int4*)(dst + (size_t)x * CIN_ + cs) = make_int4(r[0], r[1], r[2], r[3]);
        }
    } else if (bx < 584) {
        // ---- w_dc swizzle -> f16 A-fragments ----
        int idx = (bx - 512) * 256 + tid;   // [0, 36*8*64)
        int q   = idx >> 9;
        int rem = idx & 511;
        int ocb = rem >> 6;
        int l   = rem & 63;
        int cbq = q / 9;
        int k   = q - cbq * 9;
        int cb  = (cbq << 5) + ((l >> 4) << 3);
        int oc  = (ocb << 4) + (l & 15);
        unsigned r[4];
#pragma unroll
        for (int j = 0; j < 4; ++j) {
            float f0 = w_dc[((size_t)(oc * CIN_ + cb + 2 * j    )) * KK_ + k];
            float f1 = w_dc[((size_t)(oc * CIN_ + cb + 2 * j + 1)) * KK_ + k];
            r[j] = (unsigned)f2h(f0) | ((unsigned)f2h(f1) << 16);
        }
        *(int4*)&w_swz[(size_t)idx * 8] = make_int4(r[0], r[1], r[2], r[3]);
    } else {
        // ---- w_off swizzle -> bf16 A-fragments, oc padded 27->32 ----
        int idx = (bx - 584) * 256 + tid;   // [0, 36*2*64)
        int q   = idx >> 7;
        int rem = idx & 127;
        int l   = rem & 63;
        int cbq = q / 9;
        int k   = q - cbq * 9;
        int cb  = (cbq << 5) + ((l >> 4) << 3);
        int oc  = ((rem >> 6) << 4) + (l & 15);
        unsigned r[4];
#pragma unroll
        for (int j = 0; j < 4; ++j) {
            float f0 = 0.f, f1 = 0.f;
            if (oc < 27) {
                f0 = w_off[((size_t)(oc * CIN_ + cb + 2 * j    )) * KK_ + k];
                f1 = w_off[((size_t)(oc * CIN_ + cb + 2 * j + 1)) * KK_ + k];
            }
            r[j] = f2bf(f0) | (f2bf(f1) << 16);
        }
        *(int4*)&woff_swz[(size_t)idx * 8] = make_int4(r[0], r[1], r[2], r[3]);
    }
}

// ---------------------------------------------------------------------------
// Fused main (v6): offset-conv GEMM (phase 1, bf16, result in LDS) ->
// bilinear metadata -> deformable-conv GEMM (phase 2, f16, channel-last
// gathers). v5 regression root-caused: phase-2 lane mapping px=lane,cs=wave
// destroyed gather coalescing (64 lines/instr instead of 16) AND worsened
// LDS write conflicts (period-8 bank aliasing). Reverted to v3's measured
// mapping px=tid>>2, cs=tid&3 (quad shares a corner -> one 64B line).
// Shared memory as DISTINCT objects (s_R0 reused s_F<->s_V; offv/midx/mwgt
// separate) so alias analysis can schedule phase-2 ds_reads freely.
// LDS total 36716 B -> 4 blocks/CU.
// ---------------------------------------------------------------------------
__global__ __launch_bounds__(256, 4) void fused_kernel(
    const float* __restrict__ feat, const unsigned short* __restrict__ inpT,
    const unsigned short* __restrict__ woff_swz, const unsigned short* __restrict__ w_swz,
    const float* __restrict__ b_off, const float* __restrict__ b_dc,
    float* __restrict__ out)
{
    const int tid = threadIdx.x;
    const int bx = blockIdx.x;
    const int lidx = ((bx & 7) << 7) | (bx >> 3);   // XCD swizzle, 1024 blocks
    const int b  = lidx >> 8;
    const int h  = (lidx & 255) >> 1;
    const int w0 = (lidx & 1) << 6;                 // == pw0

    __shared__ __align__(16) unsigned short s_R0[7936];   // 15872B: s_F / s_V
    __shared__ float  offv[27][65];                       // 7020B
    __shared__ int2   s_midx[576];                        // 4608B
    __shared__ float4 s_mwgt[576];                        // 9216B

    unsigned short (*s_F)[66][40] = (unsigned short (*)[66][40])s_R0;   // phase 1
    unsigned short (*s_V)[64][40] = (unsigned short (*)[64][40])s_R0;   // phase 2

    const int lane = tid & 63;
    const int wave = tid >> 6;
    const int kg = lane >> 4, pn = lane & 15;

    // ================= phase 1: offset conv (bf16 MFMA) =================
    {
        const float* fbase = feat + (size_t)b * CIN_ * HW_;
        f32x4 acc[2];
        acc[0] = (f32x4){0.f, 0.f, 0.f, 0.f};
        acc[1] = (f32x4){0.f, 0.f, 0.f, 0.f};

        for (int cb = 0; cb < 4; ++cb) {
            if (cb) __syncthreads();       // taps of cb-1 done reading s_F

#pragma unroll
            for (int r = 0; r < 3; ++r) {
                const int y = h + r - 1;
                const bool yv = (unsigned)y < (unsigned)H_;   // block-uniform
                const float* rowp = fbase + (size_t)(cb << 5) * HW_ + y * W_;
#pragma unroll
                for (int j = 0; j < 4; ++j) {
                    int item = tid + (j << 8);
                    int c = item >> 5;
                    int e = item & 31;
                    int x0 = w0 - 1 + 2 * e;
                    int hx = min(max(x0, 0), W_ - 2);
                    float v0 = 0.f, v1 = 0.f;
                    if (yv) {
                        f2v p = *(const f2v*)(rowp + (size_t)c * HW_ + hx);
                        v0 = (x0 == hx) ? p.x : ((x0 < hx) ? 0.f : p.y);
                        v1 = (x0 == hx) ? p.y : ((x0 < hx) ? p.x : 0.f);
                    }
                    s_F[r][2 * e    ][c] = (unsigned short)f2bf(v0);
                    s_F[r][2 * e + 1][c] = (unsigned short)f2bf(v1);
                }
                if (tid < 32) {
                    int c = tid;
                    int x0 = w0 + 63;
                    int hx = min(x0, W_ - 2);
                    float v0 = 0.f, v1 = 0.f;
                    if (yv) {
                        f2v p = *(const f2v*)(rowp + (size_t)c * HW_ + hx);
                        v0 = (x0 == hx) ? p.x : p.y;
                        v1 = (x0 == hx) ? p.y : 0.f;
                    }
                    s_F[r][64][c] = (unsigned short)f2bf(v0);
                    s_F[r][65][c] = (unsigned short)f2bf(v1);
                }
            }
            __syncthreads();

            const int qb2 = cb * 18;
            const short8* wb = (const short8*)woff_swz;
            short8 a0 = wb[(size_t)(qb2    ) * 64 + lane];
            short8 a1 = wb[(size_t)(qb2 + 1) * 64 + lane];
#pragma unroll
            for (int k = 0; k < 9; ++k) {
                const int ky = k / 3, kx = k - 3 * ky;
                short8 bfr = *(const short8*)&s_F[ky][wave * 16 + pn + kx][kg * 8];
                short8 na0, na1;
                if (k < 8) {
                    na0 = wb[(size_t)(qb2 + 2 * k + 2) * 64 + lane];
                    na1 = wb[(size_t)(qb2 + 2 * k + 3) * 64 + lane];
                }
                acc[0] = __builtin_amdgcn_mfma_f32_16x16x32_bf16(a0, bfr, acc[0], 0, 0, 0);
                acc[1] = __builtin_amdgcn_mfma_f32_16x16x32_bf16(a1, bfr, acc[1], 0, 0, 0);
                if (k < 8) { a0 = na0; a1 = na1; }
            }
        }

        // epilogue -> offv (LDS, f32 — identical numerics to global offm)
        const int row0 = (lane >> 4) << 2;
        const int col  = lane & 15;
        const int pwl  = wave * 16 + col;
#pragma unroll
        for (int mt = 0; mt < 2; ++mt) {
#pragma unroll
            for (int i = 0; i < 4; ++i) {
                int oc = mt * 16 + row0 + i;
                if (oc < 27) {
                    float v = acc[mt][i] + b_off[oc];
                    if (oc >= 18) v = 1.f / (1.f + __expf(-v));
                    offv[oc][pwl] = v;
                }
            }
        }
    }
    __syncthreads();   // offv visible to all

    // ================= bilinear metadata: 9 taps x 64 px =================
    for (int i = tid; i < 576; i += 256) {
        int k = i >> 6, p = i & 63;
        int ky = k / 3, kx = k - ky * 3;
        int pw = w0 + p;
        float offy = offv[2 * k    ][p];
        float offx = offv[2 * k + 1][p];
        float mask = offv[18 + k   ][p];
        float py  = offy + (float)(h  + ky - 1);
        float px_ = offx + (float)(pw + kx - 1);
        float y0f = floorf(py), x0f = floorf(px_);
        float ly = py - y0f, lx = px_ - x0f;
        int y0 = (int)y0f, x0 = (int)x0f;
        int y1 = y0 + 1;
        int hx = min(max(x0, 0), W_ - 2);
        float wlo = 0.f, whi = 0.f;
        if (x0 == hx)          { wlo = 1.f - lx; whi = lx; }     // normal
        else if (x0 == hx - 1) { wlo = lx; }                     // x0 == -1
        else if (x0 == hx + 1) { whi = 1.f - lx; }               // x0 == W-1
        float wt_top = ((unsigned)y0 < (unsigned)H_) ? (1.f - ly) * mask : 0.f;
        float wt_bot = ((unsigned)y1 < (unsigned)H_) ? ly * mask : 0.f;
        int cy0 = min(max(y0, 0), H_ - 1), cy1 = min(max(y1, 0), H_ - 1);
        s_midx[i] = make_int2(cy0 * W_ + hx, cy1 * W_ + hx);
        s_mwgt[i] = make_float4(wt_top * wlo, wt_top * whi,
                                wt_bot * wlo, wt_bot * whi);
    }
    __syncthreads();   // meta visible; offv dead; s_R0 reusable as s_V

    // ================= phase 2: deformable conv (f16 MFMA) =================
    const int px = tid >> 2;              // gather pixel; quad shares a corner
    const int cs = tid & 3;               // channel quarter (8 ch)
    const char* inpTb = (const char*)(inpT + (size_t)b * CIN_ * HW_);

    f32x4 acc2[2][4];
#pragma unroll
    for (int mt = 0; mt < 2; ++mt)
#pragma unroll
        for (int nt = 0; nt < 4; ++nt) acc2[mt][nt] = (f32x4){0.f, 0.f, 0.f, 0.f};

    h8 pf0, pf1, pf2, pf3;   // corners: (y0,x0),(y0,x1),(y1,x0),(y1,x1)

    auto issue = [&](int qq) {
        int cbq = qq / 9;
        int k   = qq - cbq * 9;
        int2 id = s_midx[(k << 6) + px];
        int coff = (cbq << 6) + (cs << 4);
        const char* g0 = inpTb + ((size_t)(unsigned)id.x << 8) + coff;
        const char* g1 = inpTb + ((size_t)(unsigned)id.y << 8) + coff;
        pf0 = *(const h8*)(g0);
        pf1 = *(const h8*)(g0 + 256);     // x+1: +CIN_*2B
        pf2 = *(const h8*)(g1);
        pf3 = *(const h8*)(g1 + 256);
    };

    issue(0);

    for (int q = 0; q < 36; ++q) {
        int k = q - (q / 9) * 9;

        // consume prefetched corners: packed-f16 bilinear
        float4 wt = s_mwgt[(k << 6) + px];
        h8 v = pf0 * (_Float16)wt.x;
        v += pf1 * (_Float16)wt.y;
        v += pf2 * (_Float16)wt.z;
        v += pf3 * (_Float16)wt.w;

        // A-fragments FIRST (so MFMA's vmcnt wait keeps gathers in flight)
        const h8* wp = (const h8*)w_swz + (size_t)(q * 8 + wave * 2) * 64 + lane;
        h8 af0 = wp[0];
        h8 af1 = wp[64];

        *(h8*)&s_V[q & 1][px][cs << 3] = v;

        int qn = (q + 1 < 36) ? q + 1 : 35;
        issue(qn);                         // gathers for next chunk in flight

        __syncthreads();                   // buf[q&1] complete; prev reads done

#pragma unroll
        for (int nt = 0; nt < 4; ++nt) {
            h8 bfr = *(const h8*)&s_V[q & 1][nt * 16 + pn][kg * 8];
            acc2[0][nt] = __builtin_amdgcn_mfma_f32_16x16x32_f16(af0, bfr, acc2[0][nt], 0, 0, 0);
            acc2[1][nt] = __builtin_amdgcn_mfma_f32_16x16x32_f16(af1, bfr, acc2[1][nt], 0, 0, 0);
        }
    }

    const int row0 = (lane >> 4) << 2;
    const int col  = lane & 15;
#pragma unroll
    for (int mt = 0; mt < 2; ++mt) {
#pragma unroll
        for (int nt = 0; nt < 4; ++nt) {
            int pw = w0 + nt * 16 + col;
#pragma unroll
            for (int i = 0; i < 4; ++i) {
                int oc = wave * 32 + mt * 16 + row0 + i;
                out[((size_t)(b * COUT_ + oc)) * HW_ + h * W_ + pw] =
                    acc2[mt][nt][i] + b_dc[oc];
            }
        }
    }
}

extern "C" void kernel_launch(void* const* d_in, const int* in_sizes, int n_in,
                              void* d_out, int out_size, void* d_ws, size_t ws_size,
                              hipStream_t stream)
{
    const float* inp   = (const float*)d_in[0];
    const float* feat  = (const float*)d_in[1];
    const float* w_off = (const float*)d_in[2];
    const float* b_off = (const float*)d_in[3];
    const float* w_dc  = (const float*)d_in[4];
    const float* b_dc  = (const float*)d_in[5];
    float* out  = (float*)d_out;
    unsigned short* w_swz    = (unsigned short*)d_ws;                        // 288 KB (f16)
    unsigned short* woff_swz = (unsigned short*)((char*)d_ws + 294912);      // 72 KB (bf16)
    unsigned short* inpT     = (unsigned short*)((char*)d_ws + 368640);      // 16 MB (f16 NHWC)

    prep_kernel<<<dim3(602), dim3(256), 0, stream>>>(inp, w_dc, w_off, inpT, w_swz, woff_swz);
    fused_kernel<<<dim3(1024), dim3(256), 0, stream>>>(feat, inpT, woff_swz, w_swz, b_off, b_dc, out);
}

// Round 7
// 163.792 us; speedup vs baseline: 1.2733x; 1.0461x over previous
//
#include <hip/hip_runtime.h>
#include <math.h>

#define B_    4
#define CIN_  128
#define COUT_ 128
#define H_    128
#define W_    128
#define HW_   (H_*W_)
#define KK_   9

typedef __attribute__((ext_vector_type(8))) short short8;
typedef __attribute__((ext_vector_type(4))) float f32x4;
typedef _Float16 h8 __attribute__((ext_vector_type(8)));
typedef float f2v __attribute__((ext_vector_type(2), aligned(4)));  // 4B-aligned pair load

static __device__ __forceinline__ unsigned short f2h(float f) {
    union { _Float16 h; unsigned short u; } v; v.h = (_Float16)f;
    return v.u;
}

// K-chunk order (both GEMMs): q = cblock*9 + tap (channel-outer, tap inner).

// ---------------------------------------------------------------------------
// Prep (fused): bx<1024 -> transpose {inp,feat} NCHW f32 -> NHWC f16;
//               bx<1096 -> w_dc swizzle (f16); else -> w_off swizzle (f16).
// ---------------------------------------------------------------------------
__global__ __launch_bounds__(256) void prep_kernel(
    const float* __restrict__ inp, const float* __restrict__ feat,
    const float* __restrict__ w_dc, const float* __restrict__ w_off,
    unsigned short* __restrict__ inpT, unsigned short* __restrict__ featT,
    unsigned short* __restrict__ w_swz, unsigned short* __restrict__ woff_swz)
{
    const int bx = blockIdx.x;
    const int tid = threadIdx.x;
    __shared__ unsigned short s_T[128 * 142];   // 36352 B (tpose branch only)

    if (bx < 1024) {
        // ---- transpose: block = (src, b, y); LDS tile [128x][142c] ----
        const int bi = bx & 511;
        const int b = bi >> 7, y = bi & 127;
        const float* src = (bx < 512 ? inp : feat) + (size_t)b * CIN_ * HW_ + y * W_;
        unsigned short* dstb = (bx < 512 ? inpT : featT) + (size_t)bi * (W_ * CIN_);
        const int xs = (tid & 63) * 2;
        const int c0 = tid >> 6;
#pragma unroll 4
        for (int p = 0; p < 32; ++p) {
            int c = c0 + 4 * p;
            f2v d = *(const f2v*)(src + (size_t)c * HW_ + xs);
            s_T[xs * 142 + c]       = f2h(d.x);
            s_T[(xs + 1) * 142 + c] = f2h(d.y);
        }
        __syncthreads();
        const int cs = (tid & 15) * 8;
        const int x0 = tid >> 4;
#pragma unroll
        for (int p = 0; p < 8; ++p) {
            int x = x0 + 16 * p;
            unsigned r[4];
#pragma unroll
            for (int j = 0; j < 4; ++j) {
                unsigned lo = s_T[x * 142 + cs + 2 * j];
                unsigned hi = s_T[x * 142 + cs + 2 * j + 1];
                r[j] = lo | (hi << 16);
            }
            *(int4*)(dstb + (size_t)x * CIN_ + cs) = make_int4(r[0], r[1], r[2], r[3]);
        }
    } else if (bx < 1096) {
        // ---- w_dc swizzle -> f16 A-fragments ----
        int idx = (bx - 1024) * 256 + tid;   // [0, 36*8*64)
        int q   = idx >> 9;
        int rem = idx & 511;
        int ocb = rem >> 6;
        int l   = rem & 63;
        int cbq = q / 9;
        int k   = q - cbq * 9;
        int cb  = (cbq << 5) + ((l >> 4) << 3);
        int oc  = (ocb << 4) + (l & 15);
        unsigned r[4];
#pragma unroll
        for (int j = 0; j < 4; ++j) {
            float f0 = w_dc[((size_t)(oc * CIN_ + cb + 2 * j    )) * KK_ + k];
            float f1 = w_dc[((size_t)(oc * CIN_ + cb + 2 * j + 1)) * KK_ + k];
            r[j] = (unsigned)f2h(f0) | ((unsigned)f2h(f1) << 16);
        }
        *(int4*)&w_swz[(size_t)idx * 8] = make_int4(r[0], r[1], r[2], r[3]);
    } else {
        // ---- w_off swizzle -> f16 A-fragments, oc padded 27->32 ----
        int idx = (bx - 1096) * 256 + tid;   // [0, 36*2*64)
        int q   = idx >> 7;
        int rem = idx & 127;
        int l   = rem & 63;
        int cbq = q / 9;
        int k   = q - cbq * 9;
        int cb  = (cbq << 5) + ((l >> 4) << 3);
        int oc  = ((rem >> 6) << 4) + (l & 15);
        unsigned r[4];
#pragma unroll
        for (int j = 0; j < 4; ++j) {
            float f0 = 0.f, f1 = 0.f;
            if (oc < 27) {
                f0 = w_off[((size_t)(oc * CIN_ + cb + 2 * j    )) * KK_ + k];
                f1 = w_off[((size_t)(oc * CIN_ + cb + 2 * j + 1)) * KK_ + k];
            }
            r[j] = (unsigned)f2h(f0) | ((unsigned)f2h(f1) << 16);
        }
        *(int4*)&woff_swz[(size_t)idx * 8] = make_int4(r[0], r[1], r[2], r[3]);
    }
}

// ---------------------------------------------------------------------------
// Fused main (v7):
// Phase 1: offset conv from featT (NHWC f16) — staging is pure 16B copies
//   (3 h8 loads + 3 ds_write_b128 per thread per cb, 2-way banks = free,
//   zero convert VALU), f16 MFMA. Replaces v6's 13 scalar loads + 24 f2bf +
//   24 byte-writes (8-way conflicts) per cb.
// Phase 2: deformable conv, f16 channel-last gathers (v3/v6 mapping), raw
//   s_barrier + lgkmcnt(0)-only (no vmcnt drain in loop). Issue order per
//   iter: gathers(q+1) then A-frags(q+1) -> compiler's counted waits are
//   vmcnt(2) at consume / vmcnt(6) at MFMA, each on loads issued a full
//   iteration earlier. WAR on s_V[q&1] safe: each thread's ds_reads are
//   lgkm-waited before its MFMAs, which precede barrier(q+1), which
//   precedes the q+2 overwrite.
// ---------------------------------------------------------------------------
__global__ __launch_bounds__(256, 4) void fused_kernel(
    const unsigned short* __restrict__ featT, const unsigned short* __restrict__ inpT,
    const unsigned short* __restrict__ woff_swz, const unsigned short* __restrict__ w_swz,
    const float* __restrict__ b_off, const float* __restrict__ b_dc,
    float* __restrict__ out)
{
    const int tid = threadIdx.x;
    const int bx = blockIdx.x;
    const int lidx = ((bx & 7) << 7) | (bx >> 3);   // XCD swizzle, 1024 blocks
    const int b  = lidx >> 8;
    const int h  = (lidx & 255) >> 1;
    const int w0 = (lidx & 1) << 6;                 // == pw0

    __shared__ __align__(16) unsigned short s_R0[7936];   // 15872B: s_F / s_V
    __shared__ float  offv[27][65];                       // 7020B
    __shared__ int2   s_midx[576];                        // 4608B
    __shared__ float4 s_mwgt[576];                        // 9216B

    unsigned short (*s_F)[66][40] = (unsigned short (*)[66][40])s_R0;   // phase 1
    unsigned short (*s_V)[64][40] = (unsigned short (*)[64][40])s_R0;   // phase 2

    const int lane = tid & 63;
    const int wave = tid >> 6;
    const int kg = lane >> 4, pn = lane & 15;

    // ================= phase 1: offset conv (f16 MFMA, featT staging) =======
    {
        const unsigned short* fT = featT;   // [b][y][x][c] f16
        f32x4 acc[2];
        acc[0] = (f32x4){0.f, 0.f, 0.f, 0.f};
        acc[1] = (f32x4){0.f, 0.f, 0.f, 0.f};

        const int me = tid >> 2;      // main px 0..63 (tile-x me+1)
        const int mg = tid & 3;       // ch-group of 8

        for (int cb = 0; cb < 4; ++cb) {
            if (cb) __syncthreads();       // taps of cb-1 done reading s_F

            // main tile: 3 rows x 64 px x 32 ch, one h8 copy per thread per row
#pragma unroll
            for (int r = 0; r < 3; ++r) {
                int y = h + r - 1;
                h8 d{};
                if ((unsigned)y < (unsigned)H_)
                    d = *(const h8*)(fT + (((size_t)(b * H_ + y) * W_ + (w0 + me)) * CIN_
                                           + (cb << 5) + (mg << 3)));
                *(h8*)&s_F[r][me + 1][mg << 3] = d;
            }
            // halo px: tile-x 0 (x=w0-1) and 65 (x=w0+64), 24 items
            if (tid < 24) {
                int r = tid >> 3, side = (tid >> 2) & 1, g = tid & 3;
                int x = side ? (w0 + 64) : (w0 - 1);
                int t = side ? 65 : 0;
                int y = h + r - 1;
                h8 d{};
                if (((unsigned)y < (unsigned)H_) & ((unsigned)x < (unsigned)W_))
                    d = *(const h8*)(fT + (((size_t)(b * H_ + y) * W_ + x) * CIN_
                                           + (cb << 5) + (g << 3)));
                *(h8*)&s_F[r][t][g << 3] = d;
            }
            __syncthreads();

            const int qb2 = cb * 18;
            const h8* wb = (const h8*)woff_swz;
            h8 a0 = wb[(size_t)(qb2    ) * 64 + lane];
            h8 a1 = wb[(size_t)(qb2 + 1) * 64 + lane];
#pragma unroll
            for (int k = 0; k < 9; ++k) {
                const int ky = k / 3, kx = k - 3 * ky;
                h8 bfr = *(const h8*)&s_F[ky][wave * 16 + pn + kx][kg * 8];
                h8 na0, na1;
                if (k < 8) {
                    na0 = wb[(size_t)(qb2 + 2 * k + 2) * 64 + lane];
                    na1 = wb[(size_t)(qb2 + 2 * k + 3) * 64 + lane];
                }
                acc[0] = __builtin_amdgcn_mfma_f32_16x16x32_f16(a0, bfr, acc[0], 0, 0, 0);
                acc[1] = __builtin_amdgcn_mfma_f32_16x16x32_f16(a1, bfr, acc[1], 0, 0, 0);
                if (k < 8) { a0 = na0; a1 = na1; }
            }
        }

        // epilogue -> offv (LDS, f32)
        const int row0 = (lane >> 4) << 2;
        const int col  = lane & 15;
        const int pwl  = wave * 16 + col;
#pragma unroll
        for (int mt = 0; mt < 2; ++mt) {
#pragma unroll
            for (int i = 0; i < 4; ++i) {
                int oc = mt * 16 + row0 + i;
                if (oc < 27) {
                    float v = acc[mt][i] + b_off[oc];
                    if (oc >= 18) v = 1.f / (1.f + __expf(-v));
                    offv[oc][pwl] = v;
                }
            }
        }
    }
    __syncthreads();   // offv visible to all

    // ================= bilinear metadata: 9 taps x 64 px =================
    for (int i = tid; i < 576; i += 256) {
        int k = i >> 6, p = i & 63;
        int ky = k / 3, kx = k - ky * 3;
        int pw = w0 + p;
        float offy = offv[2 * k    ][p];
        float offx = offv[2 * k + 1][p];
        float mask = offv[18 + k   ][p];
        float py  = offy + (float)(h  + ky - 1);
        float px_ = offx + (float)(pw + kx - 1);
        float y0f = floorf(py), x0f = floorf(px_);
        float ly = py - y0f, lx = px_ - x0f;
        int y0 = (int)y0f, x0 = (int)x0f;
        int y1 = y0 + 1;
        int hx = min(max(x0, 0), W_ - 2);
        float wlo = 0.f, whi = 0.f;
        if (x0 == hx)          { wlo = 1.f - lx; whi = lx; }     // normal
        else if (x0 == hx - 1) { wlo = lx; }                     // x0 == -1
        else if (x0 == hx + 1) { whi = 1.f - lx; }               // x0 == W-1
        float wt_top = ((unsigned)y0 < (unsigned)H_) ? (1.f - ly) * mask : 0.f;
        float wt_bot = ((unsigned)y1 < (unsigned)H_) ? ly * mask : 0.f;
        int cy0 = min(max(y0, 0), H_ - 1), cy1 = min(max(y1, 0), H_ - 1);
        s_midx[i] = make_int2(cy0 * W_ + hx, cy1 * W_ + hx);
        s_mwgt[i] = make_float4(wt_top * wlo, wt_top * whi,
                                wt_bot * wlo, wt_bot * whi);
    }
    __syncthreads();   // meta visible; offv dead; s_R0 reusable as s_V

    // ================= phase 2: deformable conv (f16 MFMA) =================
    const int px = tid >> 2;              // gather pixel; quad shares a corner
    const int cs = tid & 3;               // channel quarter (8 ch)
    const char* inpTb = (const char*)(inpT + (size_t)b * CIN_ * HW_);

    f32x4 acc2[2][4];
#pragma unroll
    for (int mt = 0; mt < 2; ++mt)
#pragma unroll
        for (int nt = 0; nt < 4; ++nt) acc2[mt][nt] = (f32x4){0.f, 0.f, 0.f, 0.f};

    h8 pf0, pf1, pf2, pf3;   // corners: (y0,x0),(y0,x1),(y1,x0),(y1,x1)

    auto issue = [&](int qq) {
        int cbq = qq / 9;
        int k   = qq - cbq * 9;
        int2 id = s_midx[(k << 6) + px];
        int coff = (cbq << 6) + (cs << 4);
        const char* g0 = inpTb + ((size_t)(unsigned)id.x << 8) + coff;
        const char* g1 = inpTb + ((size_t)(unsigned)id.y << 8) + coff;
        pf0 = *(const h8*)(g0);
        pf1 = *(const h8*)(g0 + 256);     // x+1: +CIN_*2B
        pf2 = *(const h8*)(g1);
        pf3 = *(const h8*)(g1 + 256);
    };

    issue(0);
    const h8* wp0 = (const h8*)w_swz + (size_t)(wave * 2) * 64 + lane;
    h8 af0 = wp0[0];
    h8 af1 = wp0[64];

    for (int q = 0; q < 36; ++q) {
        int k = q - (q / 9) * 9;

        // consume prefetched corners (vmcnt-counted wait, loads 1 iter old)
        float4 wt = s_mwgt[(k << 6) + px];
        h8 v = pf0 * (_Float16)wt.x;
        v += pf1 * (_Float16)wt.y;
        v += pf2 * (_Float16)wt.z;
        v += pf3 * (_Float16)wt.w;

        *(h8*)&s_V[q & 1][px][cs << 3] = v;

        int qn = (q + 1 < 36) ? q + 1 : 35;
        issue(qn);                         // gathers first...
        const h8* wpn = (const h8*)w_swz + (size_t)(qn * 8 + wave * 2) * 64 + lane;
        h8 na0 = wpn[0];                   // ...then A-frags (newest in queue)
        h8 na1 = wpn[64];

        // lgkm-only barrier: ds_write visible, gathers stay in flight
        asm volatile("s_waitcnt lgkmcnt(0)" ::: "memory");
        __builtin_amdgcn_s_barrier();
        __builtin_amdgcn_sched_barrier(0);

#pragma unroll
        for (int nt = 0; nt < 4; ++nt) {
            h8 bfr = *(const h8*)&s_V[q & 1][nt * 16 + pn][kg * 8];
            acc2[0][nt] = __builtin_amdgcn_mfma_f32_16x16x32_f16(af0, bfr, acc2[0][nt], 0, 0, 0);
            acc2[1][nt] = __builtin_amdgcn_mfma_f32_16x16x32_f16(af1, bfr, acc2[1][nt], 0, 0, 0);
        }
        af0 = na0; af1 = na1;
    }

    const int row0 = (lane >> 4) << 2;
    const int col  = lane & 15;
#pragma unroll
    for (int mt = 0; mt < 2; ++mt) {
#pragma unroll
        for (int nt = 0; nt < 4; ++nt) {
            int pw = w0 + nt * 16 + col;
#pragma unroll
            for (int i = 0; i < 4; ++i) {
                int oc = wave * 32 + mt * 16 + row0 + i;
                out[((size_t)(b * COUT_ + oc)) * HW_ + h * W_ + pw] =
                    acc2[mt][nt][i] + b_dc[oc];
            }
        }
    }
}

extern "C" void kernel_launch(void* const* d_in, const int* in_sizes, int n_in,
                              void* d_out, int out_size, void* d_ws, size_t ws_size,
                              hipStream_t stream)
{
    const float* inp   = (const float*)d_in[0];
    const float* feat  = (const float*)d_in[1];
    const float* w_off = (const float*)d_in[2];
    const float* b_off = (const float*)d_in[3];
    const float* w_dc  = (const float*)d_in[4];
    const float* b_dc  = (const float*)d_in[5];
    float* out  = (float*)d_out;
    unsigned short* w_swz    = (unsigned short*)d_ws;                        // 288 KB (f16)
    unsigned short* woff_swz = (unsigned short*)((char*)d_ws + 294912);      // 72 KB (f16)
    unsigned short* inpT     = (unsigned short*)((char*)d_ws + 368640);      // 16 MB (f16 NHWC)
    unsigned short* featT    = (unsigned short*)((char*)d_ws + 368640 + 16777216);  // 16 MB

    prep_kernel<<<dim3(1114), dim3(256), 0, stream>>>(inp, feat, w_dc, w_off,
                                                      inpT, featT, w_swz, woff_swz);
    fused_kernel<<<dim3(1024), dim3(256), 0, stream>>>(featT, inpT, woff_swz, w_swz,
                                                       b_off, b_dc, out);
}